// Round 4
// baseline (73375.226 us; speedup 1.0000x reference)
//
#include <hip/hip_runtime.h>
#include <stdint.h>

// ---------------------------------------------------------------------------
// Tacotron2-style decoder, 400 sequential steps. R4: barrier de-contention +
// 4 phases/step.
//   R3 post-mortem: ~32us/phase fixed cost, independent of payload. Theory:
//   255 blocks spin-polling ONE release word with agent-scope (MALL) loads
//   -> single-line contention inflates release observation to tens of us.
//   R4: (1) 8 release lines (32 pollers each) + s_sleep backoff;
//       (2) 5 -> 4 barriers/step: gate blocks do cell updates IN-BLOCK via
//           LDS (GATT/GDEC buffers deleted); q recomputed per energies block
//           from L2-hot qW; dec proj runs in next step's phase 1.
// Phases: F1 att-gates+att-cell + loc-conv/SBUF + proj(t-1);
//         F2 q + energies + A-pack; F3 softmax + ctx; F4 dec-gates+dec-cell.
// Coherence: cross-block state via relaxed agent-scope atomics (write-through,
// no cache maintenance anywhere). Weights/private data normal cached.
// ---------------------------------------------------------------------------

#define NB  32
#define TI  512
#define ED  576
#define TO  400
#define NM  80
#define PR  256
#define AR  1024
#define DR  1024
#define AD  128
#define NFl 32
#define KSz 31
#define KA  1856
#define KD  2624
#define NKT_A 58
#define NKT_D 82

typedef __attribute__((ext_vector_type(8))) short bf8_t;
typedef __attribute__((ext_vector_type(4))) float f4_t;
typedef __attribute__((ext_vector_type(2))) float f2_t;
typedef unsigned long long ull;

__device__ __forceinline__ short f2bf(float f){
  union { float f; unsigned u; } v; v.f = f;
  unsigned r = v.u + 0x7fffu + ((v.u >> 16) & 1u);
  return (short)(r >> 16);
}
__device__ __forceinline__ float bf2f(short s){
  union { unsigned u; float f; } v; v.u = ((unsigned)(unsigned short)s) << 16; return v.f;
}
__device__ __forceinline__ float sigm(float x){ return 1.f / (1.f + __expf(-x)); }

__device__ __forceinline__ f4_t MFMA(bf8_t a, bf8_t b, f4_t c){
  return __builtin_amdgcn_mfma_f32_16x16x32_bf16(a, b, c, 0, 0, 0);
}

// ---- coherent (agent-scope relaxed) accessors ------------------------------
__device__ __forceinline__ float cld(const float* p){
  return __hip_atomic_load(p, __ATOMIC_RELAXED, __HIP_MEMORY_SCOPE_AGENT);
}
__device__ __forceinline__ void cst(float* p, float v){
  __hip_atomic_store(p, v, __ATOMIC_RELAXED, __HIP_MEMORY_SCOPE_AGENT);
}
__device__ __forceinline__ ull cld8(const void* p){
  return __hip_atomic_load((const ull*)p, __ATOMIC_RELAXED, __HIP_MEMORY_SCOPE_AGENT);
}
__device__ __forceinline__ void cst8(void* p, ull v){
  __hip_atomic_store((ull*)p, v, __ATOMIC_RELAXED, __HIP_MEMORY_SCOPE_AGENT);
}
__device__ __forceinline__ bf8_t cld_bf8(const short* p){
  union { bf8_t v; ull q[2]; } u;
  u.q[0] = cld8(p); u.q[1] = cld8(p + 4);
  return u.v;
}
__device__ __forceinline__ void cst_bf8(short* p, bf8_t v){
  union { bf8_t v; ull q[2]; } u; u.v = v;
  cst8(p, u.q[0]); cst8(p + 4, u.q[1]);
}

__device__ __forceinline__ bf8_t packrow(const float* p){   // cached source
  f4_t a = *(const f4_t*)p;
  f4_t b = *(const f4_t*)(p + 4);
  bf8_t r;
  r[0]=f2bf(a[0]); r[1]=f2bf(a[1]); r[2]=f2bf(a[2]); r[3]=f2bf(a[3]);
  r[4]=f2bf(b[0]); r[5]=f2bf(b[1]); r[6]=f2bf(b[2]); r[7]=f2bf(b[3]);
  return r;
}
__device__ __forceinline__ bf8_t packrow_coh(const float* p){ // coherent source
  union { ull q; float f[2]; } u0, u1, u2, u3;
  u0.q = cld8(p); u1.q = cld8(p + 2); u2.q = cld8(p + 4); u3.q = cld8(p + 6);
  bf8_t r;
  r[0]=f2bf(u0.f[0]); r[1]=f2bf(u0.f[1]);
  r[2]=f2bf(u1.f[0]); r[3]=f2bf(u1.f[1]);
  r[4]=f2bf(u2.f[0]); r[5]=f2bf(u2.f[1]);
  r[6]=f2bf(u3.f[0]); r[7]=f2bf(u3.f[1]);
  return r;
}

struct Par {
  const float *X2, *PMEM;
  const short *WA, *WD, *QWB, *WLOC, *MEMBT, *PJW;
  const float *BSA, *BSD;
  const float *convW, *convb, *vW;
  const float *projb, *gateb;
  const int *mlen;
  float *SBUF, *AC, *DH, *DC, *CTX, *AW, *AWC, *EN;
  short *ABA, *ABD;
  float *out_mel, *out_gate, *out_align;
  unsigned *FLAGS;
};

// att input = [x_t(256) | ctx_{t-1}(576) | ac_{t-1}(1024)]
__device__ __forceinline__ const float* aptr_att(const Par& p, int rp, int t, int b, int k){
  if (k < PR)      return p.X2 + ((size_t)t*NB + b)*PR + k;
  if (k < PR+ED)   return p.CTX + (size_t)rp*NB*ED + b*ED + (k - PR);
  return p.AC + (size_t)rp*NB*AR + b*AR + (k - PR - ED);
}

// ---- grid barrier: 8 release lines (64B apart), s_sleep backoff ------------
__device__ __forceinline__ void gbar(unsigned* flags, unsigned tgt){
  __syncthreads();
  if (threadIdx.x == 0)
    __hip_atomic_store(&flags[blockIdx.x], tgt, __ATOMIC_RELAXED, __HIP_MEMORY_SCOPE_AGENT);
  if (blockIdx.x == 0){
    if (threadIdx.x < 256){
      while (__hip_atomic_load(&flags[threadIdx.x], __ATOMIC_RELAXED, __HIP_MEMORY_SCOPE_AGENT) < tgt)
        __builtin_amdgcn_s_sleep(1);
    }
    __syncthreads();
    if (threadIdx.x < 8)
      __hip_atomic_store(&flags[256 + (threadIdx.x << 4)], tgt, __ATOMIC_RELAXED, __HIP_MEMORY_SCOPE_AGENT);
  } else if (threadIdx.x == 0){
    const int j = 256 + ((blockIdx.x & 7) << 4);
    while (__hip_atomic_load(&flags[j], __ATOMIC_RELAXED, __HIP_MEMORY_SCOPE_AGENT) < tgt)
      __builtin_amdgcn_s_sleep(2);
  }
  __syncthreads();
}

// ---- 8-wave accumulator reduce -> wave 0 (LDS only) ------------------------
__device__ __forceinline__ void reduce8(float* red, f4_t& a0, f4_t& a1, int lane, int wv){
  float* slot = red + (size_t)(wv*64 + lane)*12;
  *(f4_t*)slot       = a0;
  *(f4_t*)(slot + 4) = a1;
  __syncthreads();
  if (wv == 0){
    #pragma unroll
    for (int w = 1; w < 8; ++w){
      const float* s2 = red + (size_t)(w*64 + lane)*12;
      f4_t b0 = *(const f4_t*)s2;
      f4_t b1 = *(const f4_t*)(s2 + 4);
      a0 += b0; a1 += b1;
    }
  }
  __syncthreads();
}

// ---- mel/gate projection for step tprev (blocks 0..31, b = bid) ------------
__device__ void proj_out(const Par& p, int b, int tprev, int tid, float* sDH, float* sCTX){
  const float* ctxg = p.CTX + (size_t)(tprev & 1)*NB*ED + b*ED;
  for (int k = tid; k < ED; k += 512) sCTX[k] = cld(ctxg + k);
  for (int u = tid; u < DR; u += 512) sDH[u] = cld(&p.DH[(size_t)b*DR + u]);
  __syncthreads();
  const int lane = tid & 63, wv = tid >> 6;
  for (int o = wv; o < 81; o += 8){
    const short* wr = p.PJW + (size_t)o*1600;
    float s = 0.f;
    for (int k = lane; k < 1600; k += 64){
      float in = (k < DR) ? sDH[k] : sCTX[k - DR];
      s += in * bf2f(wr[k]);
    }
    #pragma unroll
    for (int d = 32; d > 0; d >>= 1) s += __shfl_down(s, d);
    if (lane == 0){
      if (o < 80) p.out_mel[((size_t)b*NM + o)*TO + tprev] = s + p.projb[o];
      else        p.out_gate[(size_t)b*TO + tprev] = s + p.gateb[0];
    }
  }
}

// ============================ persistent kernel =============================
__global__ __launch_bounds__(512) void k_loop(Par p){
  const int bid = blockIdx.x, tid = threadIdx.x;
  const int lane = tid & 63, wv = tid >> 6;
  __shared__ float smem[6144];

  for (int t = 0; t < TO; ++t){
    const int wp = t & 1, rp = wp ^ 1;
    const unsigned base = (unsigned)(t * 4);

    // ===== F1: att-gates MFMA + in-block att-cell + loc-conv + proj(t-1) ===
    {
      f4_t acc0 = (f4_t){0.f,0.f,0.f,0.f}, acc1 = (f4_t){0.f,0.f,0.f,0.f};
      for (int ks = wv; ks < NKT_A; ks += 8){
        bf8_t a0, a1;
        if (t == 0 || (ks >= 8 && ks < 26)){            // ctx span (or step 0)
          const int kb = ks*32 + ((lane >> 4) << 3);
          const float* p0 = aptr_att(p, rp, t, lane & 15, kb);
          const float* p1 = aptr_att(p, rp, t, 16 + (lane & 15), kb);
          if (kb < PR){ a0 = packrow(p0);     a1 = packrow(p1);     }
          else        { a0 = packrow_coh(p0); a1 = packrow_coh(p1); }
        } else {
          a0 = cld_bf8(p.ABA + ((size_t)(0*NKT_A + ks)*64 + lane)*8);
          a1 = cld_bf8(p.ABA + ((size_t)(1*NKT_A + ks)*64 + lane)*8);
        }
        const bf8_t bw = *(const bf8_t*)(p.WA + ((size_t)(bid*NKT_A + ks)*64 + lane)*8);
        acc0 = MFMA(a0, bw, acc0);
        acc1 = MFMA(a1, bw, acc1);
      }
      reduce8(smem, acc0, acc1, lane, wv);
      if (wv == 0){                      // gate tile -> LDS sG[batch][col16]
        const int col = lane & 15, rb2 = (lane >> 4) << 2;
        const int jp = (col & 3)*1024 + bid*4 + (col >> 2);
        const float bs = p.BSA[jp];
        #pragma unroll
        for (int r = 0; r < 4; ++r){
          smem[(rb2 + r)*17 + col]      = acc0[r] + bs;
          smem[(16 + rb2 + r)*17 + col] = acc1[r] + bs;
        }
      }
      __syncthreads();
      if (tid < 128){                    // att cell for 4 units x 32 batches
        const int b = tid & 31, ul = tid >> 5;
        const int u = bid*4 + ul;
        const float gi = smem[b*17 + ul*4 + 0];
        const float gf = smem[b*17 + ul*4 + 1];
        const float gg = smem[b*17 + ul*4 + 2];
        const float c = sigm(gf) * cld(&p.AC[(size_t)rp*NB*AR + b*AR + u])
                      + sigm(gi) * tanhf(gg);
        cst(&p.AC[(size_t)wp*NB*AR + b*AR + u], c);   // ref: h overwritten by c
      }
      __syncthreads();
      // location conv + loc-proj -> SBUF, job (b = bid>>3, tc = bid&7)
      {
        const int b = bid >> 3, tc = bid & 7, t0 = tc*64;
        float* sAWI = smem + 600;                 // [94][2]
        short* sCwB = (short*)(smem + 800);       // [64][40] bf16
        for (int i = tid; i < 94; i += 512){
          int g = t0 - 15 + i;
          float a = 0.f, w = 0.f;
          if (g >= 0 && g < TI){
            a = cld(&p.AW [(size_t)rp*NB*TI + b*TI + g]);
            w = cld(&p.AWC[(size_t)rp*NB*TI + b*TI + g]);
          }
          sAWI[2*i] = a; sAWI[2*i + 1] = w;
        }
        __syncthreads();
        {
          const int wvu = __builtin_amdgcn_readfirstlane(wv);
          const int f0 = wvu * 4;
          float ac4[4];
          #pragma unroll
          for (int ff = 0; ff < 4; ++ff) ac4[ff] = p.convb[f0 + ff];
          for (int k = 0; k < KSz; ++k){
            f2_t a2 = *(const f2_t*)&sAWI[2*(lane + k)];
            #pragma unroll
            for (int ff = 0; ff < 4; ++ff){
              ac4[ff] += a2[0] * p.convW[((f0+ff)*2 + 0)*KSz + k]
                       + a2[1] * p.convW[((f0+ff)*2 + 1)*KSz + k];
            }
          }
          #pragma unroll
          for (int ff = 0; ff < 4; ++ff) sCwB[lane*40 + f0 + ff] = f2bf(ac4[ff]);
        }
        __syncthreads();
        for (int j = wv; j < 32; j += 8){
          const int mt = j >> 3, nt2 = j & 7;
          const bf8_t afr = *(const bf8_t*)(sCwB + (mt*16 + (lane & 15))*40 + ((lane >> 4) << 3));
          const bf8_t bfr = *(const bf8_t*)(p.WLOC + (size_t)(nt2*64 + lane)*8);
          f4_t c = (f4_t){0.f,0.f,0.f,0.f};
          c = MFMA(afr, bfr, c);
          const int tl2 = mt*16 + ((lane >> 4) << 2);
          const int d2  = nt2*16 + (lane & 15);
          #pragma unroll
          for (int r = 0; r < 4; ++r){
            const int tg2 = t0 + tl2 + r;
            p.SBUF[((size_t)b*TI + tg2)*AD + d2] =
              c[r] + p.PMEM[((size_t)b*TI + tg2)*AD + d2];
          }
        }
      }
      if (bid < NB && t > 0) proj_out(p, bid, t - 1, tid, smem + 3072, smem + 4160);
    }
    gbar(p.FLAGS, base + 1);

    // ===== F2: q (redundant per block) + energies + A-pack ==================
    {
      float* sAC = smem;           // 1024
      float* sQ  = smem + 1056;    // 128
      const int b = bid >> 3, tc = bid & 7;
      if (tid < 512){
        union { ull q; float f[2]; } u2;
        u2.q = cld8(&p.AC[(size_t)wp*NB*AR + b*AR + tid*2]);
        sAC[tid*2] = u2.f[0]; sAC[tid*2 + 1] = u2.f[1];
      }
      // A-pack on wave 7 of blocks < 208 (doesn't touch sAC/sQ)
      if (wv == 7 && bid < 208){
        const int r = lane & 15, koff = (lane >> 4) << 3;
        if (bid < 80){
          if (t < TO - 1){  // att A for t+1: x / ac parts
            const int m = bid / 40, idx = bid % 40;
            const int ks = (idx < 8) ? idx : idx + 18;
            const int row = m*16 + r;
            const int k = ks*32 + koff;
            bf8_t v = (k < PR)
              ? packrow(p.X2 + ((size_t)(t+1)*NB + row)*PR + k)
              : packrow_coh(p.AC + (size_t)wp*NB*AR + (size_t)row*AR + (k - PR - ED));
            cst_bf8(p.ABA + ((size_t)(m*NKT_A + ks)*64 + lane)*8, v);
          }
        } else {            // dec A for this step: ac / dh parts
          const int j2 = bid - 80;
          const int m = j2 / 64, idx = j2 % 64;
          const int ks = (idx < 32) ? idx : idx + 18;
          const int row = m*16 + r;
          const int k = ks*32 + koff;
          bf8_t v = (k < AR)
            ? packrow_coh(p.AC + (size_t)wp*NB*AR + (size_t)row*AR + k)
            : packrow_coh(p.DH + (size_t)row*DR + (k - AR - ED));
          cst_bf8(p.ABD + ((size_t)(m*NKT_D + ks)*64 + lane)*8, v);
        }
      }
      __syncthreads();
      // q rows d = wv*16 .. +15  (qWB plain [128][1024] bf16, L2-hot)
      for (int rr = 0; rr < 16; ++rr){
        const int d = wv*16 + rr;
        const short* qr = p.QWB + (size_t)d*AR;
        float s = 0.f;
        #pragma unroll
        for (int i = 0; i < 8; ++i){
          const unsigned pk = *(const unsigned*)(qr + i*128 + lane*2);
          s += bf2f((short)(pk & 0xffff)) * sAC[i*128 + lane*2]
             + bf2f((short)(pk >> 16))    * sAC[i*128 + lane*2 + 1];
        }
        #pragma unroll
        for (int d2 = 32; d2 > 0; d2 >>= 1) s += __shfl_down(s, d2);
        if (lane == 0) sQ[d] = s;
      }
      __syncthreads();
      // energies
      const int tl = tid >> 3, dq = tid & 7;
      const int tg = tc*64 + tl;
      const float* sb = p.SBUF + ((size_t)b*TI + tg)*AD;
      float s = 0.f;
      #pragma unroll
      for (int j = 0; j < 16; ++j){
        const int d = dq*16 + j;
        s += p.vW[d] * tanhf(sQ[d] + sb[d]);
      }
      s += __shfl_down(s, 1);
      s += __shfl_down(s, 2);
      s += __shfl_down(s, 4);
      if (dq == 0)
        cst(&p.EN[b*TI + tg], (tg < p.mlen[b]) ? s : -1e30f);
    }
    gbar(p.FLAGS, base + 2);

    // ===== F3: softmax + context ============================================
    {
      const int b = bid >> 3, ec = bid & 7;
      float* red = smem;
      float* sp  = smem + 512;
      const float e = cld(&p.EN[b*TI + tid]);
      red[tid] = e; __syncthreads();
      for (int s2 = 256; s2 > 0; s2 >>= 1){
        if (tid < s2) red[tid] = fmaxf(red[tid], red[tid + s2]);
        __syncthreads();
      }
      const float M = red[0]; __syncthreads();
      const float x = __expf(e - M);
      red[tid] = x; __syncthreads();
      for (int s2 = 256; s2 > 0; s2 >>= 1){
        if (tid < s2) red[tid] += red[tid + s2];
        __syncthreads();
      }
      const float Z = red[0]; __syncthreads();
      const float pv = x / Z;
      sp[tid] = pv;
      __syncthreads();
      if (ec == 0){
        cst(&p.AW [(size_t)wp*NB*TI + b*TI + tid], pv);
        cst(&p.AWC[(size_t)wp*NB*TI + b*TI + tid],
            cld(&p.AWC[(size_t)rp*NB*TI + b*TI + tid]) + pv);
        p.out_align[((size_t)b*TO + t)*TI + tid] = pv;
      }
      for (int ii = 0; ii < 9; ++ii){
        const int e2 = ec*72 + wv*9 + ii;
        const short* row = p.MEMBT + ((size_t)b*ED + e2)*TI;
        float a2 = 0.f;
        #pragma unroll
        for (int c = 0; c < 8; ++c)
          a2 += sp[c*64 + lane] * bf2f(row[c*64 + lane]);
        #pragma unroll
        for (int d = 32; d > 0; d >>= 1) a2 += __shfl_down(a2, d);
        if (lane == 0)
          cst(&p.CTX[(size_t)wp*NB*ED + b*ED + e2], a2);
      }
    }
    gbar(p.FLAGS, base + 3);

    // ===== F4: dec-gates MFMA + in-block dec-cell ==========================
    {
      f4_t acc0 = (f4_t){0.f,0.f,0.f,0.f}, acc1 = (f4_t){0.f,0.f,0.f,0.f};
      for (int ks = wv; ks < NKT_D; ks += 8){
        bf8_t a0, a1;
        if (ks >= 32 && ks < 50){                       // ctx span (coherent)
          const int kb = ks*32 + ((lane >> 4) << 3);
          const float* c0 = p.CTX + (size_t)wp*NB*ED + (size_t)(lane & 15)*ED + (kb - AR);
          const float* c1 = p.CTX + (size_t)wp*NB*ED + (size_t)(16 + (lane & 15))*ED + (kb - AR);
          a0 = packrow_coh(c0);
          a1 = packrow_coh(c1);
        } else {
          a0 = cld_bf8(p.ABD + ((size_t)(0*NKT_D + ks)*64 + lane)*8);
          a1 = cld_bf8(p.ABD + ((size_t)(1*NKT_D + ks)*64 + lane)*8);
        }
        const bf8_t bw = *(const bf8_t*)(p.WD + ((size_t)(bid*NKT_D + ks)*64 + lane)*8);
        acc0 = MFMA(a0, bw, acc0);
        acc1 = MFMA(a1, bw, acc1);
      }
      reduce8(smem, acc0, acc1, lane, wv);
      if (wv == 0){
        const int col = lane & 15, rb2 = (lane >> 4) << 2;
        const int jp = (col & 3)*1024 + bid*4 + (col >> 2);
        const float bs = p.BSD[jp];
        #pragma unroll
        for (int r = 0; r < 4; ++r){
          smem[(rb2 + r)*17 + col]      = acc0[r] + bs;
          smem[(16 + rb2 + r)*17 + col] = acc1[r] + bs;
        }
      }
      __syncthreads();
      if (tid < 128){                    // dec cell for 4 units x 32 batches
        const int b = tid & 31, ul = tid >> 5;
        const int u = bid*4 + ul;
        const float gi = smem[b*17 + ul*4 + 0];
        const float gf = smem[b*17 + ul*4 + 1];
        const float gg = smem[b*17 + ul*4 + 2];
        const float go = smem[b*17 + ul*4 + 3];
        const float c = sigm(gf) * p.DC[(size_t)b*DR + u] + sigm(gi) * tanhf(gg);
        p.DC[(size_t)b*DR + u] = c;                       // block-private
        cst(&p.DH[(size_t)b*DR + u], sigm(go) * tanhf(c));
      }
    }
    gbar(p.FLAGS, base + 4);
  }

  if (bid < NB) proj_out(p, bid, TO - 1, tid, smem, smem + 1088);
}

// ============================ setup kernels =================================
__global__ __launch_bounds__(256) void k_init(float* z, int nz,
                                              float* bsa, const float* a1, const float* a2,
                                              float* bsd, const float* d1, const float* d2){
  const int idx = blockIdx.x*256 + threadIdx.x, st = gridDim.x*256;
  for (int i = idx; i < nz; i += st) z[i] = 0.f;
  for (int i = idx; i < 4096; i += st){ bsa[i] = a1[i] + a2[i]; bsd[i] = d1[i] + d2[i]; }
}

__global__ __launch_bounds__(256) void k_prenet1(const float* di, const float* W1, float* X1){
  const int t = blockIdx.x, tid = threadIdx.x;
  __shared__ float sdi[NB*NM];
  for (int i = tid; i < NB*NM; i += 256){
    const int b = i / NM, k = i - b*NM;
    sdi[i] = (t == 0) ? 0.f : di[((size_t)b*TO + (t-1))*NM + k];
  }
  __syncthreads();
  float acc[NB];
  #pragma unroll
  for (int b = 0; b < NB; ++b) acc[b] = 0.f;
  const int j = tid;
  for (int k = 0; k < NM; ++k){
    const float w = W1[j*NM + k];
    #pragma unroll
    for (int b = 0; b < NB; ++b) acc[b] += sdi[b*NM + k] * w;
  }
  for (int b = 0; b < NB; ++b)
    X1[((size_t)t*NB + b)*PR + j] = fmaxf(acc[b], 0.f);
}

__global__ __launch_bounds__(256) void k_prenet2(const float* X1, const float* W2, float* X2){
  const int t = blockIdx.x, tid = threadIdx.x;
  __shared__ float sx[NB*PR];
  for (int i = tid; i < NB*PR; i += 256) sx[i] = X1[(size_t)t*NB*PR + i];
  __syncthreads();
  float acc[NB];
  #pragma unroll
  for (int b = 0; b < NB; ++b) acc[b] = 0.f;
  const int j = tid;
  for (int k = 0; k < PR; ++k){
    const float w = W2[j*PR + k];
    #pragma unroll
    for (int b = 0; b < NB; ++b) acc[b] += sx[b*PR + k] * w;
  }
  for (int b = 0; b < NB; ++b)
    X2[((size_t)t*NB + b)*PR + j] = fmaxf(acc[b], 0.f);
}

__global__ __launch_bounds__(256) void k_pmem(const float* mem, const float* memW, float* pm){
  const int b = blockIdx.x >> 3, tc = blockIdx.x & 7, tid = threadIdx.x;
  __shared__ float sW[64*AD];
  __shared__ float sM[64*65];
  const int tl = tid >> 2, dq = tid & 3;
  float acc[32];
  #pragma unroll
  for (int i = 0; i < 32; ++i) acc[i] = 0.f;
  for (int kc = 0; kc < 9; ++kc){
    __syncthreads();
    for (int i = tid; i < 64*AD; i += 256){
      const int d = i >> 6, kl = i & 63;
      sW[kl*AD + ((d + kl) & 127)] = memW[(size_t)d*ED + kc*64 + kl];
    }
    for (int i = tid; i < 64*64; i += 256){
      const int tt = i >> 6, kl = i & 63;
      sM[tt*65 + kl] = mem[((size_t)b*TI + tc*64 + tt)*ED + kc*64 + kl];
    }
    __syncthreads();
    for (int kl = 0; kl < 64; ++kl){
      const float mv = sM[tl*65 + kl];
      #pragma unroll
      for (int d2 = 0; d2 < 32; ++d2)
        acc[d2] += mv * sW[kl*AD + ((dq*32 + d2 + kl) & 127)];
    }
  }
  for (int d2 = 0; d2 < 32; ++d2)
    pm[((size_t)b*TI + tc*64 + tl)*AD + dq*32 + d2] = acc[d2];
}

__global__ __launch_bounds__(256) void k_membt(const float* mem, short* mt){
  const int b = blockIdx.x / 36, ec = blockIdx.x % 36;
  __shared__ float sT[64*17];
  for (int tc = 0; tc < 8; ++tc){
    __syncthreads();
    for (int i = threadIdx.x; i < 64*16; i += 256){
      const int tt = i >> 4, e = i & 15;
      sT[tt*17 + e] = mem[((size_t)b*TI + tc*64 + tt)*ED + ec*16 + e];
    }
    __syncthreads();
    for (int i = threadIdx.x; i < 16*64; i += 256){
      const int e = i >> 6, tt = i & 63;
      mt[((size_t)b*ED + ec*16 + e)*TI + tc*64 + tt] = f2bf(sT[tt*17 + e]);
    }
  }
}

__global__ __launch_bounds__(64) void k_swz_gate(const float* Wih, const float* Whh,
                                                 short* dst, int split, int nkt){
  const int bidx = blockIdx.x;
  const int nt = bidx / nkt, kt = bidx - nt*nkt;
  const int lane = threadIdx.x;
  const int nl = lane & 15;
  const int jp = (nl & 3)*1024 + nt*4 + (nl >> 2);
  const int k0 = kt*32 + ((lane >> 4) << 3);
  bf8_t v;
  #pragma unroll
  for (int jj = 0; jj < 8; ++jj){
    const int k = k0 + jj;
    const float f = (k < split) ? Wih[(size_t)jp*split + k]
                                : Whh[(size_t)jp*1024 + (k - split)];
    v[jj] = f2bf(f);
  }
  *(bf8_t*)(dst + (size_t)bidx*512 + lane*8) = v;
}

__global__ __launch_bounds__(256) void k_qwb(const float* qW, short* dst){
  const int idx = blockIdx.x*256 + threadIdx.x, st = gridDim.x*256;
  for (int i = idx; i < AD*AR; i += st) dst[i] = f2bf(qW[i]);
}

__global__ __launch_bounds__(64) void k_swz_loc(const float* locW, short* dst){
  const int nt = blockIdx.x;
  const int lane = threadIdx.x;
  const int d = nt*16 + (lane & 15);
  const int f0 = (lane >> 4) << 3;
  bf8_t v;
  #pragma unroll
  for (int jj = 0; jj < 8; ++jj) v[jj] = f2bf(locW[d*NFl + f0 + jj]);
  *(bf8_t*)(dst + (size_t)(nt*64 + lane)*8) = v;
}

__global__ __launch_bounds__(256) void k_swz_proj(const float* projW, const float* gateW,
                                                  short* dst){
  const int o = blockIdx.x;
  const float* src = (o < 80) ? (projW + (size_t)o*1600) : gateW;
  for (int k = threadIdx.x; k < 1600; k += 256)
    dst[(size_t)o*1600 + k] = f2bf(src[k]);
}

// ============================== launch ======================================
extern "C" void kernel_launch(void* const* d_in, const int* in_sizes, int n_in,
                              void* d_out, int out_size, void* d_ws, size_t ws_size,
                              hipStream_t stream){
  const float* mem    = (const float*)d_in[0];
  const float* dec_in = (const float*)d_in[1];
  const float* pW1    = (const float*)d_in[2];
  const float* pW2    = (const float*)d_in[3];
  const float* aWih   = (const float*)d_in[4];
  const float* aWhh   = (const float*)d_in[5];
  const float* aBih   = (const float*)d_in[6];
  const float* aBhh   = (const float*)d_in[7];
  const float* qW     = (const float*)d_in[8];
  const float* memW   = (const float*)d_in[9];
  const float* convW  = (const float*)d_in[10];
  const float* convb  = (const float*)d_in[11];
  const float* locW   = (const float*)d_in[12];
  const float* vW     = (const float*)d_in[13];
  const float* dWih   = (const float*)d_in[14];
  const float* dWhh   = (const float*)d_in[15];
  const float* dBih   = (const float*)d_in[16];
  const float* dBhh   = (const float*)d_in[17];
  const float* projW  = (const float*)d_in[18];
  const float* projb  = (const float*)d_in[19];
  const float* gateW  = (const float*)d_in[20];
  const float* gateb  = (const float*)d_in[21];
  const int*   mlen   = (const int*)d_in[22];
  (void)in_sizes; (void)n_in; (void)out_size; (void)ws_size;

  char* basep = (char*)d_ws;
  size_t off = 0;
  auto carve = [&](size_t bytes) -> char* {
    char* r = basep + off;
    off = (off + bytes + 255) & ~(size_t)255;
    return r;
  };
  short* WA    = (short*)carve((size_t)4096*KA*2);
  short* WD    = (short*)carve((size_t)4096*KD*2);
  short* QWB   = (short*)carve((size_t)AD*AR*2);
  short* WLOC  = (short*)carve((size_t)AD*NFl*2);
  short* MEMBT = (short*)carve((size_t)NB*TI*ED*2);
  short* PJW   = (short*)carve((size_t)81*1600*2);
  float* X1    = (float*)carve((size_t)TO*NB*PR*4);
  float* X2    = (float*)carve((size_t)TO*NB*PR*4);
  float* PMEM  = (float*)carve((size_t)NB*TI*AD*4);
  float* SBUF  = (float*)carve((size_t)NB*TI*AD*4);
  float* BSA   = (float*)carve((size_t)4096*4);
  float* BSD   = (float*)carve((size_t)4096*4);
  short* ABA   = (short*)carve((size_t)2*NKT_A*512*2);
  short* ABD   = (short*)carve((size_t)2*NKT_D*512*2);
  // ---- zero-span begins here (contiguous through FLAGS) ----
  float* AC    = (float*)carve((size_t)2*NB*AR*4);
  float* DH    = (float*)carve((size_t)NB*DR*4);
  float* DC    = (float*)carve((size_t)NB*DR*4);
  float* CTX   = (float*)carve((size_t)2*NB*ED*4);
  float* AW    = (float*)carve((size_t)2*NB*TI*4);
  float* AWC   = (float*)carve((size_t)2*NB*TI*4);
  float* EN    = (float*)carve((size_t)NB*TI*4);
  unsigned* FLAGS = (unsigned*)carve(4096);
  const int nz = (int)((((char*)FLAGS + 4096) - (char*)AC) / 4);

  float* out_mel   = (float*)d_out;
  float* out_gate  = out_mel + (size_t)NB*NM*TO;
  float* out_align = out_gate + (size_t)NB*TO;

  k_init   <<<dim3(512), dim3(256), 0, stream>>>(AC, nz, BSA, aBih, aBhh, BSD, dBih, dBhh);
  k_prenet1<<<dim3(TO),  dim3(256), 0, stream>>>(dec_in, pW1, X1);
  k_prenet2<<<dim3(TO),  dim3(256), 0, stream>>>(X1, pW2, X2);
  k_pmem   <<<dim3(256), dim3(256), 0, stream>>>(mem, memW, PMEM);
  k_membt  <<<dim3(NB*36), dim3(256), 0, stream>>>(mem, MEMBT);
  k_swz_gate<<<dim3(256*NKT_A), dim3(64), 0, stream>>>(aWih, aWhh, WA, 832, NKT_A);
  k_swz_gate<<<dim3(256*NKT_D), dim3(64), 0, stream>>>(dWih, dWhh, WD, 1600, NKT_D);
  k_qwb    <<<dim3(128), dim3(256), 0, stream>>>(qW, QWB);
  k_swz_loc<<<dim3(8),   dim3(64), 0, stream>>>(locW, WLOC);
  k_swz_proj<<<dim3(81), dim3(256), 0, stream>>>(projW, gateW, PJW);

  Par p;
  p.X2 = X2; p.PMEM = PMEM;
  p.WA = WA; p.WD = WD; p.QWB = QWB; p.WLOC = WLOC; p.MEMBT = MEMBT; p.PJW = PJW;
  p.BSA = BSA; p.BSD = BSD;
  p.convW = convW; p.convb = convb; p.vW = vW;
  p.projb = projb; p.gateb = gateb;
  p.mlen = mlen;
  p.SBUF = SBUF;
  p.AC = AC; p.DH = DH; p.DC = DC; p.CTX = CTX;
  p.AW = AW; p.AWC = AWC; p.EN = EN;
  p.ABA = ABA; p.ABD = ABD;
  p.out_mel = out_mel; p.out_gate = out_gate; p.out_align = out_align;
  p.FLAGS = FLAGS;

  k_loop<<<dim3(256), dim3(512), 0, stream>>>(p);
}